// Round 8
// baseline (138.519 us; speedup 1.0000x reference)
//
#include <hip/hip_runtime.h>
#include <hip/hip_bf16.h>

// ---------------------------------------------------------------------------
// NattenBlock: qkv GEMM -> 7x7 NATTEN (GQA 12q/4kv, D=64) -> out GEMM.
// 2048 pixels (2x32x32), d_model 768.
// Round 8: 3 dispatches (convert kernel eliminated). GEMMs consume fp32
// operands directly: regs -> v_cvt_pk_bf16_f32 -> ds_write_b128 staging
// (pitch-40 LDS, ~4-way max conflicts). gemm2's bf16 A keeps
// global_load_lds (pitch-32, R4-proven). Core GEMM = R4 64x64/BK=128.
// ---------------------------------------------------------------------------

typedef __attribute__((ext_vector_type(8))) __bf16 bf16x8;
typedef __attribute__((ext_vector_type(4))) float floatx4;
typedef unsigned short u16;

__device__ inline u16 f2bf(float f) {
    union { float f; unsigned u; } v; v.f = f;
    return (u16)((v.u + 0x7fff + ((v.u >> 16) & 1)) >> 16);   // RNE
}

__device__ inline void gl_lds16(const void* g, void* l) {
    __builtin_amdgcn_global_load_lds(
        (const __attribute__((address_space(1))) void*)g,
        (__attribute__((address_space(3))) void*)l, 16, 0, 0);
}

// 8 fp32 -> 8 bf16 (RNE, hw v_cvt_pk_bf16_f32) packed as uint4.
__device__ inline uint4 pack8(float4 a, float4 b) {
    union { __hip_bfloat162 h[4]; uint4 u; } r;
    r.h[0] = __float22bfloat162_rn(float2{a.x, a.y});
    r.h[1] = __float22bfloat162_rn(float2{a.z, a.w});
    r.h[2] = __float22bfloat162_rn(float2{b.x, b.y});
    r.h[3] = __float22bfloat162_rn(float2{b.z, b.w});
    return r.u;
}

// C = A[M,K] @ B[N,K]^T, fp32 accum. Tile 64Mx64N, BK=128 (4 kc of 32),
// 256 thr = 4 waves, wave quadrant 32x32 = 2x2 MFMA tiles of 16x16x32.
// B is ALWAYS fp32 global, staged via regs+cvt_pk+ds_write into pitch-40 LDS.
// MODE 1 (qkv GEMM): A = x fp32 (same staging); epilogue col<1024 -> bf16
//   Cb[row*1024+col], col>=1024 -> transposed bf16 vT[(col-1024)*2048+row].
// MODE 0 (out GEMM): A = bf16 (global_load_lds, pitch-32); fp32 C[M,N].
template<int MODE>
__global__ __launch_bounds__(256) void gemm_nt(
    const void* __restrict__ Ain, const float* __restrict__ Bf,
    float* __restrict__ C, u16* __restrict__ Cb, u16* __restrict__ vT,
    int N, int K)
{
    __shared__ __align__(16) u16 As[MODE ? 4 * 2560 : 4 * 2048]; // 20/16 KB
    __shared__ __align__(16) u16 Bs[4 * 2560];                   // 20 KB
    const int tid = threadIdx.x;
    const int lane = tid & 63;
    const int wave = tid >> 6;
    const int bm = blockIdx.y * 64;
    const int bn = blockIdx.x * 64;
    const int qr = (wave >> 1) * 32;
    const int qc = (wave & 1) * 32;

    floatx4 acc[2][2] = {};

    // fp32 staging mapping: thread -> (row = tid>>2, kc = tid&3), 32 f32.
    const int srow = tid >> 2;
    const int skc  = tid & 3;
    const float* Bsrc = Bf + (size_t)(bn + srow) * K + skc * 32;
    u16* Bdst = &Bs[skc * 2560 + srow * 40];
    const float* Asrc = nullptr; u16* Adst = nullptr;
    if (MODE) {
        Asrc = (const float*)Ain + (size_t)(bm + srow) * K + skc * 32;
        Adst = &As[skc * 2560 + srow * 40];
    }
    // MODE0: A bf16 via global_load_lds, pitch-32 m97 layout, 16 chunks/iter.
    int gA[4], lA[4];
    if (!MODE) {
        #pragma unroll
        for (int i = 0; i < 4; i++) {
            int c = wave + 4 * i, kc = c & 3, rg = c >> 2;
            gA[i] = (bm + rg * 16 + (lane >> 2)) * K + kc * 32 + (lane & 3) * 8;
            lA[i] = kc * 2048 + rg * 512 + lane * 8;
        }
    }

    const int fr = lane & 15;
    const int fk = (lane >> 4) * 8;
    const int nk = K >> 7;               // K/128 = 6

    for (int it = 0; it < nk; it++) {
        const int k0 = it * 128;
        {   // stage B: 32 f32 -> 4x ds_write_b128
            const float* p = Bsrc + k0;
            #pragma unroll
            for (int sg = 0; sg < 4; sg++) {
                float4 u = *(const float4*)(p + sg * 8);
                float4 v = *(const float4*)(p + sg * 8 + 4);
                *(uint4*)&Bdst[sg * 8] = pack8(u, v);
            }
        }
        if (MODE) {  // stage A fp32
            const float* p = Asrc + k0;
            #pragma unroll
            for (int sg = 0; sg < 4; sg++) {
                float4 u = *(const float4*)(p + sg * 8);
                float4 v = *(const float4*)(p + sg * 8 + 4);
                *(uint4*)&Adst[sg * 8] = pack8(u, v);
            }
        } else {     // stage A bf16 via async glds
            const u16* Ab = (const u16*)Ain;
            #pragma unroll
            for (int i = 0; i < 4; i++)
                gl_lds16(Ab + gA[i] + k0, &As[lA[i]]);
        }
        __syncthreads();
        #pragma unroll
        for (int kc = 0; kc < 4; kc++) {
            const int ap = MODE ? kc * 2560 : kc * 2048;
            const int aw = MODE ? 40 : 32;
            bf16x8 af0 = *(const bf16x8*)&As[ap + (qr +      fr) * aw + fk];
            bf16x8 af1 = *(const bf16x8*)&As[ap + (qr + 16 + fr) * aw + fk];
            bf16x8 bf0 = *(const bf16x8*)&Bs[kc * 2560 + (qc +      fr) * 40 + fk];
            bf16x8 bf1 = *(const bf16x8*)&Bs[kc * 2560 + (qc + 16 + fr) * 40 + fk];
            acc[0][0] = __builtin_amdgcn_mfma_f32_16x16x32_bf16(af0, bf0, acc[0][0], 0, 0, 0);
            acc[0][1] = __builtin_amdgcn_mfma_f32_16x16x32_bf16(af0, bf1, acc[0][1], 0, 0, 0);
            acc[1][0] = __builtin_amdgcn_mfma_f32_16x16x32_bf16(af1, bf0, acc[1][0], 0, 0, 0);
            acc[1][1] = __builtin_amdgcn_mfma_f32_16x16x32_bf16(af1, bf1, acc[1][1], 0, 0, 0);
        }
        __syncthreads();
    }

    // C/D layout: col = lane&15, row = (lane>>4)*4 + r.
    const int cr = (lane >> 4) * 4;
    const int ccol = lane & 15;
    #pragma unroll
    for (int i = 0; i < 2; i++) {
        #pragma unroll
        for (int j = 0; j < 2; j++) {
            const int row0 = bm + qr + i * 16 + cr;
            const int col  = bn + qc + j * 16 + ccol;
            if (MODE == 0) {
                #pragma unroll
                for (int r = 0; r < 4; r++)
                    C[(size_t)(row0 + r) * N + col] = acc[i][j][r];
            } else {
                if (col < 1024) {
                    #pragma unroll
                    for (int r = 0; r < 4; r++)
                        Cb[(size_t)(row0 + r) * 1024 + col] = f2bf(acc[i][j][r]);
                } else {
                    ushort4 w;
                    w.x = f2bf(acc[i][j][0]); w.y = f2bf(acc[i][j][1]);
                    w.z = f2bf(acc[i][j][2]); w.w = f2bf(acc[i][j][3]);
                    *(ushort4*)&vT[(size_t)(col - 1024) * 2048 + row0] = w;
                }
            }
        }
    }
}

// NATTEN 7x7 MFMA. Block = (q-head h, 8x8 pixel tile). 4 waves x 16 queries.
// KV union = 14x14 patch at wu = clip(tile-3, 0, 18); n = a*16+b, masked.
__global__ __launch_bounds__(256) void natten_mfma(
    const u16* __restrict__ qkv, const u16* __restrict__ vT,
    u16* __restrict__ o)
{
    __shared__ __align__(16) u16 Ks[224 * 72];
    __shared__ __align__(16) u16 Vs[64 * 224];
    __shared__ __align__(16) u16 Pw[4 * 512];
    const int h  = blockIdx.x;        // 0..11
    const int tb = blockIdx.y;        // 0..31
    const int g  = h & 3;
    const int batch = tb >> 4;
    const int ti = ((tb >> 2) & 3) * 8;
    const int tj = (tb & 3) * 8;
    const int wu_i = min(max(ti - 3, 0), 18);
    const int wu_j = min(max(tj - 3, 0), 18);
    const int tid = threadIdx.x, lane = tid & 63, wave = tid >> 6;
    const int pixbase = batch << 10;

    for (int c = tid; c < 1792; c += 256) {
        int n = c >> 3, seg = (c & 7) * 8;
        int a = n >> 4, b = min(n & 15, 13);
        int pix = pixbase + (wu_i + a) * 32 + wu_j + b;
        *(uint4*)&Ks[n * 72 + seg] =
            *(const uint4*)&qkv[(size_t)pix * 1024 + 768 + g * 64 + seg];
    }
    {
        const int b  = lane & 15;
        const int ar = lane >> 4;
        bool vok[4]; int voff[4];
        #pragma unroll
        for (int rr = 0; rr < 4; rr++) {
            int a = ar + rr * 4;
            vok[rr]  = (a < 14) && (b < 14);
            voff[rr] = (wu_i + a) * 32 + wu_j + b;
        }
        const u16* vsrc = &vT[(size_t)(g * 64 + wave * 16) * 2048 + pixbase];
        #pragma unroll 4
        for (int dd = 0; dd < 16; dd++) {
            #pragma unroll
            for (int rr = 0; rr < 4; rr++) {
                int a = ar + rr * 4;
                if (a < 14)
                    Vs[(wave * 16 + dd) * 224 + rr * 64 + lane] =
                        vok[rr] ? vsrc[voff[rr]] : (u16)0;
            }
            vsrc += 2048;
        }
    }
    __syncthreads();

    const int fr = lane & 15;
    const int fk = (lane >> 4) * 8;

    bf16x8 aq0, aq1;
    {
        int qq = wave * 16 + fr;
        int pixq = pixbase + (ti + (qq >> 3)) * 32 + tj + (qq & 7);
        const u16* qp = &qkv[(size_t)pixq * 1024 + h * 64];
        aq0 = *(const bf16x8*)(qp + fk);
        aq1 = *(const bf16x8*)(qp + 32 + fk);
    }

    bool colok[4]; int tlo[4], thi[4];
    #pragma unroll
    for (int r = 0; r < 4; r++) {
        int qq = wave * 16 + (lane >> 4) * 4 + r;
        int qi = ti + (qq >> 3), qj = tj + (qq & 7);
        int si = min(max(qi - 3, 0), 25);
        int sj = min(max(qj - 3, 0), 25);
        colok[r] = (fr < 14) && (wu_j + fr >= sj) && (wu_j + fr <= sj + 6);
        tlo[r] = si - wu_i; thi[r] = tlo[r] + 6;
    }

    float s[14][4];
    float mx[4] = {-1e30f, -1e30f, -1e30f, -1e30f};
    #pragma unroll
    for (int t = 0; t < 14; t++) {
        bf16x8 bk0 = *(const bf16x8*)&Ks[(t * 16 + fr) * 72 + fk];
        bf16x8 bk1 = *(const bf16x8*)&Ks[(t * 16 + fr) * 72 + 32 + fk];
        floatx4 a4 = {};
        a4 = __builtin_amdgcn_mfma_f32_16x16x32_bf16(aq0, bk0, a4, 0, 0, 0);
        a4 = __builtin_amdgcn_mfma_f32_16x16x32_bf16(aq1, bk1, a4, 0, 0, 0);
        #pragma unroll
        for (int r = 0; r < 4; r++) {
            bool v = colok[r] && (t >= tlo[r]) && (t <= thi[r]);
            s[t][r] = v ? a4[r] * 0.125f : -1e30f;
            mx[r] = fmaxf(mx[r], s[t][r]);
        }
    }
    #pragma unroll
    for (int r = 0; r < 4; r++) {
        mx[r] = fmaxf(mx[r], __shfl_xor(mx[r], 1));
        mx[r] = fmaxf(mx[r], __shfl_xor(mx[r], 2));
        mx[r] = fmaxf(mx[r], __shfl_xor(mx[r], 4));
        mx[r] = fmaxf(mx[r], __shfl_xor(mx[r], 8));
    }
    float l[4] = {0.f, 0.f, 0.f, 0.f};
    #pragma unroll
    for (int t = 0; t < 14; t++)
        #pragma unroll
        for (int r = 0; r < 4; r++) {
            float p = __expf(s[t][r] - mx[r]);
            s[t][r] = p; l[r] += p;
        }
    #pragma unroll
    for (int r = 0; r < 4; r++) {
        l[r] += __shfl_xor(l[r], 1);
        l[r] += __shfl_xor(l[r], 2);
        l[r] += __shfl_xor(l[r], 4);
        l[r] += __shfl_xor(l[r], 8);
    }
    float rinv[4];
    #pragma unroll
    for (int r = 0; r < 4; r++) rinv[r] = 1.0f / l[r];

    u16* pw = &Pw[wave * 512];
    floatx4 oacc[4] = {};
    #pragma unroll
    for (int kc = 0; kc < 7; kc++) {
        #pragma unroll
        for (int tt = 0; tt < 2; tt++) {
            int t = kc * 2 + tt;
            #pragma unroll
            for (int r = 0; r < 4; r++)
                pw[((lane >> 4) * 4 + r) * 32 + tt * 16 + fr] =
                    f2bf(s[t][r] * rinv[r]);
        }
        bf16x8 bp = *(const bf16x8*)&pw[fr * 32 + fk];
        #pragma unroll
        for (int u = 0; u < 4; u++) {
            bf16x8 av = *(const bf16x8*)&Vs[(u * 16 + fr) * 224 + kc * 32 + fk];
            oacc[u] = __builtin_amdgcn_mfma_f32_16x16x32_bf16(av, bp, oacc[u], 0, 0, 0);
        }
    }

    {
        int qq = wave * 16 + fr;
        int pixq = pixbase + (ti + (qq >> 3)) * 32 + tj + (qq & 7);
        u16* op = &o[(size_t)pixq * 768 + h * 64];
        #pragma unroll
        for (int u = 0; u < 4; u++) {
            ushort4 w;
            w.x = f2bf(oacc[u][0]); w.y = f2bf(oacc[u][1]);
            w.z = f2bf(oacc[u][2]); w.w = f2bf(oacc[u][3]);
            *(ushort4*)(op + u * 16 + (lane >> 4) * 4) = w;
        }
    }
}

extern "C" void kernel_launch(void* const* d_in, const int* in_sizes, int n_in,
                              void* d_out, int out_size, void* d_ws, size_t ws_size,
                              hipStream_t stream)
{
    const float* x     = (const float*)d_in[0];   // (2048, 768)
    const float* w_qkv = (const float*)d_in[1];   // (1280, 768)
    const float* w_out = (const float*)d_in[2];   // (768, 768)
    float* out = (float*)d_out;                   // (2048, 768) fp32

    char* ws = (char*)d_ws;
    u16* qkvb = (u16*)ws; ws += (size_t)2048 * 1024 * 2;   // q|k bf16, 4 MB
    u16* vTb  = (u16*)ws; ws += (size_t)256 * 2048 * 2;    // v^T bf16, 1 MB
    u16* ob   = (u16*)ws;                                  // attn out, 3 MB

    // 1) qkv = x @ w_qkv^T (fp32 in, inline cvt_pk staging)
    gemm_nt<1><<<dim3(1280 / 64, 2048 / 64), dim3(256), 0, stream>>>(
        x, w_qkv, nullptr, qkvb, vTb, 1280, 768);
    // 2) neighborhood attention
    natten_mfma<<<dim3(12, 32), dim3(256), 0, stream>>>(qkvb, vTb, ob);
    // 3) out = o @ w_out^T (A bf16 glds, B fp32 inline cvt)
    gemm_nt<0><<<dim3(768 / 64, 2048 / 64), dim3(256), 0, stream>>>(
        ob, w_out, out, nullptr, nullptr, 768, 768);
}

// Round 9
// 104.973 us; speedup vs baseline: 1.3196x; 1.3196x over previous
//
#include <hip/hip_runtime.h>
#include <hip/hip_bf16.h>

// ---------------------------------------------------------------------------
// NattenBlock: qkv GEMM -> 7x7 NATTEN (GQA 12q/4kv, D=64) -> out GEMM.
// 2048 pixels (2x32x32), d_model 768.
// Round 9: R4 core (convert kernel + bf16 glds 64x64/BK=128 GEMM) with
//  (a) natten staging ELIMINATED: 4-aligned window origin makes K-frags
//      (16B) and V^T-frags (2x8B) direct global loads; LDS = 4KB Pw only,
//      no block barrier; masked lanes contribute via p=0.
//  (b) GEMMs flipped (qkv^T = w_qkv @ x^T, out^T = w_out @ o^T): same inner
//      loop, vectorized epilogues (ushort4 / float4 on the dim axis).
// ---------------------------------------------------------------------------

typedef __attribute__((ext_vector_type(8))) __bf16 bf16x8;
typedef __attribute__((ext_vector_type(4))) float floatx4;
typedef unsigned short u16;

__device__ inline u16 f2bf(float f) {
    union { float f; unsigned u; } v; v.f = f;
    return (u16)((v.u + 0x7fff + ((v.u >> 16) & 1)) >> 16);   // RNE
}

__device__ inline void gl_lds16(const void* g, void* l) {
    __builtin_amdgcn_global_load_lds(
        (const __attribute__((address_space(1))) void*)g,
        (__attribute__((address_space(3))) void*)l, 16, 0, 0);
}

// fp32 -> bf16 for x (393216 f4), w_qkv (245760 f4), w_out (147456 f4).
__global__ __launch_bounds__(256) void convert_kernel(
    const float* __restrict__ x, const float* __restrict__ w1,
    const float* __restrict__ w2, u16* __restrict__ xb,
    u16* __restrict__ w1b, u16* __restrict__ w2b)
{
    int t = blockIdx.x * blockDim.x + threadIdx.x;   // 0..786431
    const float* s; u16* d;
    if (t < 393216)      { s = x;  d = xb; }
    else if (t < 638976) { s = w1; d = w1b; t -= 393216; }
    else                 { s = w2; d = w2b; t -= 638976; }
    float4 v = ((const float4*)s)[t];
    ushort4 o;
    o.x = f2bf(v.x); o.y = f2bf(v.y); o.z = f2bf(v.z); o.w = f2bf(v.w);
    ((ushort4*)d)[t] = o;
}

// Flipped GEMM-NT: C'[dim, pix] = A[dim,K] @ B[pix,K]^T, bf16 in, fp32 acc.
// Tile 64x64, BK=128 (4 kc of [64][32], m97 layout), glds staging (R4-proven:
// waves 0,1 stage As chunks, waves 2,3 stage Bs; 8x 1KB chunks each).
// MODE 1 (qkv): A=w_qkv(1280), B=x(2048); dim<1024 -> qkvb[pix*1024+dim]
//   (ushort4), dim>=1024 -> vT[(dim-1024)*2048+pix] (scalar).
// MODE 0 (out): A=w_out(768), B=o(2048); out[pix*768+dim] float4.
template<int MODE>
__global__ __launch_bounds__(256) void gemm_nt(
    const u16* __restrict__ A, const u16* __restrict__ B,
    float* __restrict__ out, u16* __restrict__ Cq, u16* __restrict__ vT,
    int K)
{
    __shared__ __align__(16) u16 As[4 * 2048];   // 16 KB [kc][row][32]
    __shared__ __align__(16) u16 Bs[4 * 2048];
    const int tid = threadIdx.x;
    const int lane = tid & 63;
    const int wave = tid >> 6;
    const int bm = blockIdx.y * 64;   // dim tile (A rows)
    const int bn = blockIdx.x * 64;   // pixel tile (B rows)
    const int qr = (wave >> 1) * 32;
    const int qc = (wave & 1) * 32;

    floatx4 acc[2][2] = {};

    const u16* Xsrc = (wave < 2) ? A : B;
    const int   bx  = (wave < 2) ? bm : bn;
    u16* Xlds       = (wave < 2) ? As : Bs;
    const int half  = wave & 1;
    const int l2 = lane >> 2;
    const int l3 = (lane & 3) * 8;
    int gofs[8], lofs[8];
    #pragma unroll
    for (int cc = 0; cc < 8; cc++) {
        int c = half * 8 + cc, kc = c & 3, rg = c >> 2;
        gofs[cc] = (bx + rg * 16 + l2) * K + kc * 32 + l3;
        lofs[cc] = kc * 2048 + rg * 512;
    }

    const int fr = lane & 15;
    const int fk = (lane >> 4) * 8;
    const int nk = K >> 7;            // 6

    for (int k0 = 0; k0 < K; k0 += 128) {
        #pragma unroll
        for (int cc = 0; cc < 8; cc++)
            gl_lds16(Xsrc + gofs[cc] + k0, Xlds + lofs[cc]);
        __syncthreads();
        #pragma unroll
        for (int kc = 0; kc < 4; kc++) {
            bf16x8 af0 = *(const bf16x8*)&As[kc * 2048 + (qr +      fr) * 32 + fk];
            bf16x8 af1 = *(const bf16x8*)&As[kc * 2048 + (qr + 16 + fr) * 32 + fk];
            bf16x8 bf0 = *(const bf16x8*)&Bs[kc * 2048 + (qc +      fr) * 32 + fk];
            bf16x8 bf1 = *(const bf16x8*)&Bs[kc * 2048 + (qc + 16 + fr) * 32 + fk];
            acc[0][0] = __builtin_amdgcn_mfma_f32_16x16x32_bf16(af0, bf0, acc[0][0], 0, 0, 0);
            acc[0][1] = __builtin_amdgcn_mfma_f32_16x16x32_bf16(af0, bf1, acc[0][1], 0, 0, 0);
            acc[1][0] = __builtin_amdgcn_mfma_f32_16x16x32_bf16(af1, bf0, acc[1][0], 0, 0, 0);
            acc[1][1] = __builtin_amdgcn_mfma_f32_16x16x32_bf16(af1, bf1, acc[1][1], 0, 0, 0);
        }
        __syncthreads();
    }

    // C/D layout: col(=pixel) = lane&15, row(=dim) = (lane>>4)*4 + r.
    const int cr = (lane >> 4) * 4;
    const int ccol = lane & 15;
    #pragma unroll
    for (int i = 0; i < 2; i++) {
        #pragma unroll
        for (int j = 0; j < 2; j++) {
            const int row0 = bm + qr + i * 16 + cr;       // dim
            const int col  = bn + qc + j * 16 + ccol;     // pixel
            if (MODE == 0) {
                float4 w = {acc[i][j][0], acc[i][j][1], acc[i][j][2], acc[i][j][3]};
                *(float4*)&out[(size_t)col * 768 + row0] = w;
            } else {
                if (row0 < 1024) {
                    ushort4 w;
                    w.x = f2bf(acc[i][j][0]); w.y = f2bf(acc[i][j][1]);
                    w.z = f2bf(acc[i][j][2]); w.w = f2bf(acc[i][j][3]);
                    *(ushort4*)&Cq[(size_t)col * 1024 + row0] = w;
                } else {
                    #pragma unroll
                    for (int r = 0; r < 4; r++)
                        vT[(size_t)(row0 + r - 1024) * 2048 + col] = f2bf(acc[i][j][r]);
                }
            }
        }
    }
}

// NATTEN 7x7 MFMA, zero staging. Block = (q-head h, 8x8 pixel tile),
// 4 waves x 16 queries. Window: rows wu_i..wu_i+13 (wu_i = clip(ti-3,0,18)),
// cols oj..oj+15 (oj = clip4(tj-3) in {0,4,12,16}) — covers every query's
// 7x7 window, all in-image. n = a*16+b: a = row idx (14), b = col idx (16).
// K-frags / V^T-frags loaded directly from global (L2-resident).
__global__ __launch_bounds__(256) void natten_mfma(
    const u16* __restrict__ qkv, const u16* __restrict__ vT,
    u16* __restrict__ o)
{
    __shared__ __align__(16) u16 Pw[4 * 512];   // 4 KB, per-wave P^T chunks
    const int h  = blockIdx.x;        // 0..11
    const int tb = blockIdx.y;        // 0..31
    const int g  = h & 3;             // kv head
    const int batch = tb >> 4;
    const int ti = ((tb >> 2) & 3) * 8;
    const int tj = (tb & 3) * 8;
    const int wu_i = min(max(ti - 3, 0), 18);
    const int oj   = min(max(tj - 3, 0) & ~3, 16);
    const int lane = threadIdx.x & 63, wave = threadIdx.x >> 6;
    const int pixbase = batch << 10;

    const int fr = lane & 15;
    const int fk = (lane >> 4) * 8;   // 0,8,16,24

    // Q A-frags (query q = wave*16 + fr).
    bf16x8 aq0, aq1;
    {
        int qq = wave * 16 + fr;
        int pixq = pixbase + (ti + (qq >> 3)) * 32 + tj + (qq & 7);
        const u16* qp = &qkv[(size_t)pixq * 1024 + h * 64];
        aq0 = *(const bf16x8*)(qp + fk);
        aq1 = *(const bf16x8*)(qp + 32 + fk);
    }

    // Per-r window bounds (C-layout row = query = (lane>>4)*4 + r).
    bool colok[4]; int tlo[4], thi[4];
    #pragma unroll
    for (int r = 0; r < 4; r++) {
        int qq = wave * 16 + (lane >> 4) * 4 + r;
        int qi = ti + (qq >> 3), qj = tj + (qq & 7);
        int si = min(max(qi - 3, 0), 25);
        int sj = min(max(qj - 3, 0), 25);
        colok[r] = (oj + fr >= sj) && (oj + fr <= sj + 6);
        tlo[r] = si - wu_i; thi[r] = tlo[r] + 6;
    }

    // ---- QK^T: B-frag = K row at pix(t, fr), 16B contiguous; direct global.
    float s[14][4];
    float mx[4] = {-1e30f, -1e30f, -1e30f, -1e30f};
    #pragma unroll
    for (int t = 0; t < 14; t++) {
        int kp = pixbase + (wu_i + t) * 32 + oj + fr;
        const u16* krow = &qkv[(size_t)kp * 1024 + 768 + g * 64];
        bf16x8 bk0 = *(const bf16x8*)(krow + fk);
        bf16x8 bk1 = *(const bf16x8*)(krow + 32 + fk);
        floatx4 a4 = {};
        a4 = __builtin_amdgcn_mfma_f32_16x16x32_bf16(aq0, bk0, a4, 0, 0, 0);
        a4 = __builtin_amdgcn_mfma_f32_16x16x32_bf16(aq1, bk1, a4, 0, 0, 0);
        #pragma unroll
        for (int r = 0; r < 4; r++) {
            bool v = colok[r] && (t >= tlo[r]) && (t <= thi[r]);
            s[t][r] = v ? a4[r] * 0.125f : -1e30f;
            mx[r] = fmaxf(mx[r], s[t][r]);
        }
    }
    // ---- softmax (reduce over 16 col-lanes).
    #pragma unroll
    for (int r = 0; r < 4; r++) {
        mx[r] = fmaxf(mx[r], __shfl_xor(mx[r], 1));
        mx[r] = fmaxf(mx[r], __shfl_xor(mx[r], 2));
        mx[r] = fmaxf(mx[r], __shfl_xor(mx[r], 4));
        mx[r] = fmaxf(mx[r], __shfl_xor(mx[r], 8));
    }
    float l[4] = {0.f, 0.f, 0.f, 0.f};
    #pragma unroll
    for (int t = 0; t < 14; t++)
        #pragma unroll
        for (int r = 0; r < 4; r++) {
            float p = __expf(s[t][r] - mx[r]);
            s[t][r] = p; l[r] += p;
        }
    #pragma unroll
    for (int r = 0; r < 4; r++) {
        l[r] += __shfl_xor(l[r], 1);
        l[r] += __shfl_xor(l[r], 2);
        l[r] += __shfl_xor(l[r], 4);
        l[r] += __shfl_xor(l[r], 8);
    }
    float rinv[4];
    #pragma unroll
    for (int r = 0; r < 4; r++) rinv[r] = 1.0f / l[r];

    // ---- O^T = V^T P^T. A-frag: V^T[d = u*16+fr][n = kc*32+fk+j], j=0..7
    // -> 8 consecutive pixels at row wu_i + kc*2 + (fk>=16), col oj + (fk&8).
    // Masked n have p=0, so their (in-image) V values are harmless.
    u16* pw = &Pw[wave * 512];
    floatx4 oacc[4] = {};
    const int vrow = (fk >= 16) ? 1 : 0;
    const int vcol = oj + (fk & 8);
    #pragma unroll
    for (int kc = 0; kc < 7; kc++) {
        #pragma unroll
        for (int tt = 0; tt < 2; tt++) {
            int t = kc * 2 + tt;
            #pragma unroll
            for (int r = 0; r < 4; r++)
                pw[((lane >> 4) * 4 + r) * 32 + tt * 16 + fr] =
                    f2bf(s[t][r] * rinv[r]);
        }
        bf16x8 bp = *(const bf16x8*)&pw[fr * 32 + fk];
        const int vpix = pixbase + (wu_i + kc * 2 + vrow) * 32 + vcol;
        #pragma unroll
        for (int u = 0; u < 4; u++) {
            const u16* vp = &vT[(size_t)(g * 64 + u * 16 + fr) * 2048 + vpix];
            union { ushort4 q[2]; bf16x8 v; } av;
            av.q[0] = *(const ushort4*)vp;        // 8B-aligned (vcol%4==0)
            av.q[1] = *(const ushort4*)(vp + 4);
            oacc[u] = __builtin_amdgcn_mfma_f32_16x16x32_bf16(av.v, bp, oacc[u], 0, 0, 0);
        }
    }

    // ---- write O: lane col q = fr, rows d = u*16 + (lane>>4)*4.
    {
        int qq = wave * 16 + fr;
        int pixq = pixbase + (ti + (qq >> 3)) * 32 + tj + (qq & 7);
        u16* op = &o[(size_t)pixq * 768 + h * 64];
        #pragma unroll
        for (int u = 0; u < 4; u++) {
            ushort4 w;
            w.x = f2bf(oacc[u][0]); w.y = f2bf(oacc[u][1]);
            w.z = f2bf(oacc[u][2]); w.w = f2bf(oacc[u][3]);
            *(ushort4*)(op + u * 16 + (lane >> 4) * 4) = w;
        }
    }
}

extern "C" void kernel_launch(void* const* d_in, const int* in_sizes, int n_in,
                              void* d_out, int out_size, void* d_ws, size_t ws_size,
                              hipStream_t stream)
{
    const float* x     = (const float*)d_in[0];   // (2048, 768)
    const float* w_qkv = (const float*)d_in[1];   // (1280, 768)
    const float* w_out = (const float*)d_in[2];   // (768, 768)
    float* out = (float*)d_out;                   // (2048, 768) fp32

    char* ws = (char*)d_ws;
    u16* qkvb = (u16*)ws; ws += (size_t)2048 * 1024 * 2;      // q|k bf16, 4 MB
    u16* vTb  = (u16*)ws; ws += (size_t)256 * 2048 * 2 + 64;  // v^T bf16, 1 MB
    u16* xb   = (u16*)ws; ws += (size_t)2048 * 768 * 2;       // 3 MB
    u16* w1b  = (u16*)ws; ws += (size_t)1280 * 768 * 2;       // 2 MB
    u16* w2b  = (u16*)ws; ws += (size_t)768 * 768 * 2;        // 1.1 MB
    u16* ob   = (u16*)ws;                                     // 3 MB

    convert_kernel<<<dim3(3072), dim3(256), 0, stream>>>(x, w_qkv, w_out, xb, w1b, w2b);

    // qkv^T = w_qkv @ x^T -> qkvb[pix][dim<1024] + vT[dim-1024][pix]
    gemm_nt<1><<<dim3(2048 / 64, 1280 / 64), dim3(256), 0, stream>>>(
        w1b, xb, nullptr, qkvb, vTb, 768);

    natten_mfma<<<dim3(12, 32), dim3(256), 0, stream>>>(qkvb, vTb, ob);

    // out^T = w_out @ o^T -> out[pix][dim] (float4 on dim axis)
    gemm_nt<0><<<dim3(2048 / 64, 768 / 64), dim3(256), 0, stream>>>(
        w2b, ob, out, nullptr, nullptr, 768);
}